// Round 11
// baseline (625.266 us; speedup 1.0000x reference)
//
#include <hip/hip_runtime.h>
#include <hip/hip_bf16.h>
#include <math.h>

#define NBAG 512
#define NPB 64
#define DIM 1024
#define NCLS 53
#define NSTEP 63
#define MAXROWS 16384  // level-1 worst case: 512 bags * 32 merges
#define LMAX 8         // levels 1..LMAX via batched GEMM; deeper via k_deep
                       // (R20/R21 tile ladder: 256x128 k_fcw @ l=1 (890 TF at 512
                       //  blocks); 64x128 k_fcn @ l>=2 (gather-latency levels need
                       //  block-count: 128-tile measured 390 TF @2/CU vs 700 @4/CU).
                       //  All variants bit-exact: same per-element K order.
                       //  R22: k_deep GEMV -> 8-lane groups (3-shuffle reduce), ~5x
                       //  less chain latency per deep merge; feature-path-only reorder.)

typedef __attribute__((ext_vector_type(8))) short short8;
typedef __attribute__((ext_vector_type(4))) short short4v;
typedef __attribute__((ext_vector_type(4))) float f32x4;
typedef unsigned long long u64;

__device__ __forceinline__ short bf16bits(float x) {
  __hip_bfloat16 h = __float2bfloat16(x);
  return *reinterpret_cast<short*>(&h);
}

// fast tanh: 1 - 2/(e^{2x}+1). Feature path only — never in the node-weight
// computation (tree order must not change).
__device__ __forceinline__ float fast_tanh(float x) {
  float e = __expf(2.0f * x);
  return 1.0f - __fdividef(2.0f, e + 1.0f);
}

// global -> LDS direct copy, 16B per lane, dest = wave-uniform base + lane*16
__device__ __forceinline__ void gld16(const void* g, void* l) {
  __builtin_amdgcn_global_load_lds(
      (const __attribute__((address_space(1))) void*)g,
      (__attribute__((address_space(3))) void*)(unsigned)(uintptr_t)l,
      16, 0, 0);
}

// ---------------------------------------------------------------------------
// K1a (R15): row-parallel norms + tanh leaves + weight tail. 4 blocks/bag,
// 16 rows each -> 2048 blocks (8/CU). Bitwise-identical per-row reductions.
// ---------------------------------------------------------------------------
__global__ __launch_bounds__(256) void k_prep_a(const float* __restrict__ rep,
                                                float* __restrict__ inv_g,
                                                __hip_bfloat16* __restrict__ tfeats,
                                                const float* __restrict__ w1,
                                                __hip_bfloat16* __restrict__ w1b,
                                                const float* __restrict__ w2,
                                                __hip_bfloat16* __restrict__ w2b) {
  int blk = blockIdx.x;
  int b = blk >> 2, qr = blk & 3;
  const float* bag = rep + (size_t)b * NPB * DIM;
  int t = threadIdx.x, wave = t >> 6, lane = t & 63;

  #pragma unroll
  for (int r = 0; r < 4; r++) {
    int n = qr * 16 + wave * 4 + r;
    const float* x = bag + (size_t)n * DIM;
    float f[16];
    #pragma unroll
    for (int k = 0; k < 16; k++) f[k] = x[lane + 64 * k];
    float acc = 0.f;
    #pragma unroll
    for (int k = 0; k < 16; k++) acc += f[k] * f[k];
    __hip_bfloat16* tr = tfeats + ((((size_t)b << 6) + n) << 10);
    #pragma unroll
    for (int k = 0; k < 16; k++) {
      short o = bf16bits(fast_tanh(f[k]));
      tr[lane + 64 * k] = *reinterpret_cast<__hip_bfloat16*>(&o);
    }
    for (int off = 32; off; off >>= 1) acc += __shfl_xor(acc, off);
    if (lane == 0) inv_g[b * 64 + n] = 1.0f / sqrtf(acc);
  }

  // ---- fused weight conversion tail (elementwise -> mapping-independent)
  {
    const int nv1 = (DIM * 2 * DIM) / 4;
    const int nv2 = (DIM * DIM) / 4;
    for (int i = blk * 256 + t; i < nv1 + nv2; i += 2048 * 256) {
      if (i < nv1) {
        f32x4 v = ((const f32x4*)w1)[i];
        short4v o;
        o.x = bf16bits(v.x); o.y = bf16bits(v.y);
        o.z = bf16bits(v.z); o.w = bf16bits(v.w);
        ((short4v*)w1b)[i] = o;
      } else {
        f32x4 v = ((const f32x4*)w2)[i - nv1];
        short4v o;
        o.x = bf16bits(v.x); o.y = bf16bits(v.y);
        o.z = bf16bits(v.z); o.w = bf16bits(v.w);
        ((short4v*)w2b)[i - nv1] = o;
      }
    }
  }
}

// ---------------------------------------------------------------------------
// K1b (R15): per-bag S (pass 2), dist (pass 3), softmax -> nw. Exact proven
// summation orders; inv_n from k_prep_a via global.
// ---------------------------------------------------------------------------
__global__ __launch_bounds__(1024) void k_prep_b(const float* __restrict__ rep,
                                                 const float* __restrict__ inv_g,
                                                 float* __restrict__ nw) {
  int b = blockIdx.x;
  const float* bag = rep + (size_t)b * NPB * DIM;
  __shared__ float inv_n[NPB];
  __shared__ float dist[NPB];
  __shared__ alignas(16) float S[DIM];
  int t = threadIdx.x, wave = t >> 6, lane = t & 63;

  if (t < 64) inv_n[t] = inv_g[b * 64 + t];
  __syncthreads();

  // ---- pass 2: S, vectorized across columns; per-column n-order unchanged
  if (t < 256) {
    const f32x4* br = (const f32x4*)bag;
    f32x4 acc = (f32x4){0.f, 0.f, 0.f, 0.f};
    #pragma unroll 16
    for (int n = 0; n < NPB; n++) {
      f32x4 v = br[n * 256 + t];
      float w = inv_n[n];
      acc.x += v.x * w; acc.y += v.y * w;
      acc.z += v.z * w; acc.w += v.w * w;
    }
    ((f32x4*)S)[t] = acc;
  }
  __syncthreads();

  // ---- pass 3: dist, strided scalar loads, exact-order dot with S
  for (int n = wave; n < NPB; n += 16) {
    const float* x = bag + (size_t)n * DIM;
    float f[16];
    #pragma unroll
    for (int k = 0; k < 16; k++) f[k] = x[lane + 64 * k];
    float acc = 0.f;
    #pragma unroll
    for (int k = 0; k < 16; k++) acc += f[k] * S[lane + 64 * k];
    for (int off = 32; off; off >>= 1) acc += __shfl_xor(acc, off);
    if (lane == 0) dist[n] = acc * inv_n[n];
  }
  __syncthreads();

  if (t < 64) {
    float v = dist[t], m = v;
    for (int off = 32; off; off >>= 1) m = fmaxf(m, __shfl_xor(m, off));
    float e = expf(v - m), s = e;
    for (int off = 32; off; off >>= 1) s += __shfl_xor(s, off);
    nw[b * NPB + t] = e / s;
  }
}

// ---------------------------------------------------------------------------
// K2 (R16): packed-key two-smallest butterfly Huffman. Bit-exact.
// ---------------------------------------------------------------------------
__global__ __launch_bounds__(256) void k_merge_levels(const float* __restrict__ nw,
                                                      unsigned* __restrict__ lvlbuf,
                                                      unsigned* __restrict__ cnt) {
  int b = blockIdx.x * 4 + (threadIdx.x >> 6);
  int lane = threadIdx.x & 63;
  float w = nw[b * NPB + lane];
  bool alive = true;
  int ready = 0;
  int mycnt = 0;

  for (int t = 0; t < NSTEP; t++) {
    u64 k1 = alive ? (((u64)__float_as_uint(w) << 32) |
                      ((unsigned)lane << 6) | (unsigned)ready)
                   : ~0ull;
    u64 k2 = ~0ull;
    #pragma unroll
    for (int off = 32; off; off >>= 1) {
      u64 o1 = __shfl_xor(k1, off);
      u64 o2 = __shfl_xor(k2, off);
      if (o1 < k1) {
        k2 = (k1 < o2) ? k1 : o2;
        k1 = o1;
      } else {
        k2 = (o1 < k2) ? o1 : k2;
      }
    }
    int i1 = (int)(k1 >> 6) & 63;
    int i2 = (int)(k2 >> 6) & 63;
    float w1v = __uint_as_float((unsigned)(k1 >> 32));
    float w2v = __uint_as_float((unsigned)(k2 >> 32));
    int r1 = (int)(k1 & 63u);
    int r2 = (int)(k2 & 63u);
    int lvl = max(r1, r2) + 1;
    int rank = __shfl(mycnt, lvl - 1);
    if (lane == lvl - 1) mycnt++;
    if (lane == i1) { w = w1v + w2v; ready = lvl; }
    if (lane == i2) alive = false;
    if (lane == 0)
      lvlbuf[b * NSTEP + t] = (unsigned)i1 | ((unsigned)i2 << 6) |
                              ((unsigned)lvl << 12) | ((unsigned)rank << 18);
  }
  cnt[b * 64 + lane] = (unsigned)mycnt;
}

// K3: per-level exclusive scan over bags
__global__ __launch_bounds__(512) void k_bagscan(const unsigned* __restrict__ cnt,
                                                 unsigned* __restrict__ bagoff,
                                                 unsigned* __restrict__ levtot) {
  int l = blockIdx.x + 1;
  int b = threadIdx.x;
  __shared__ unsigned s[512];
  unsigned v = cnt[b * 64 + (l - 1)];
  s[b] = v; __syncthreads();
  for (int o = 1; o < 512; o <<= 1) {
    unsigned x = (b >= o) ? s[b - o] : 0u; __syncthreads();
    s[b] += x; __syncthreads();
  }
  bagoff[l * 512 + b] = s[b] - v;
  if (b == 511) levtot[l] = s[511];
}

// K5: scatter merges into level-sorted worklist (fused level-offset scan).
__global__ __launch_bounds__(256) void k_scatter(const unsigned* __restrict__ lvlbuf,
                                                 const unsigned* __restrict__ levtot,
                                                 const unsigned* __restrict__ bagoff,
                                                 unsigned* __restrict__ wl,
                                                 unsigned* __restrict__ off_out) {
  __shared__ unsigned off_s[65];
  int t = threadIdx.x;
  if (t < 64) {
    unsigned v = (t >= 1) ? levtot[t] : 0u;
    unsigned x = v;
    for (int o = 1; o < 64; o <<= 1) {
      unsigned y = __shfl_up(x, o);
      if (t >= o) x += y;
    }
    off_s[t] = x - v;
    if (t == 63) off_s[64] = x;
    if (blockIdx.x == 0) {
      off_out[t] = x - v;
      if (t == 63) off_out[64] = x;
    }
  }
  __syncthreads();

  int idx = blockIdx.x * 256 + t;
  int b = idx / NSTEP, st = idx % NSTEP;
  unsigned e = lvlbuf[idx];
  unsigned i1 = e & 63, i2 = (e >> 6) & 63, lvl = (e >> 12) & 63, rank = (e >> 18) & 31;
  unsigned pos = off_s[lvl] + bagoff[lvl * 512 + b] + rank;
  wl[pos] = (unsigned)b | (i1 << 9) | (i2 << 15) | ((st == NSTEP - 1 ? 1u : 0u) << 21);
}

// ---------------------------------------------------------------------------
// K7w (R20): wide-tile GEMM for level 1 (full-GPU grid). BM=256 x BN=128,
// BK=64, 8 waves, wave-tile 64x64 (4M x 2N). Proven R11/R18 body verbatim
// (bit-exact outputs). Measured 78us (890 TF) at the l=1 grid.
// ---------------------------------------------------------------------------
template <int KTOT, bool FC1>
__global__ __launch_bounds__(512) void k_fcw(const __hip_bfloat16* __restrict__ Asrc,
                                             const __hip_bfloat16* __restrict__ wB,
                                             const float* __restrict__ bias,
                                             const unsigned* __restrict__ wl,
                                             const unsigned* __restrict__ off,
                                             __hip_bfloat16* __restrict__ hbuf,
                                             __hip_bfloat16* __restrict__ tfeats,
                                             float* __restrict__ rootfeat,
                                             int level) {
  __shared__ alignas(16) short As[256 * 64];   // 32 KB
  __shared__ alignas(16) short Bs[128 * 64];   // 16 KB
  __shared__ unsigned wle[256];

  int nwg = (int)gridDim.x;
  int hw = (int)blockIdx.x;
  int q = nwg >> 3, r = nwg & 7;
  int xcd = hw & 7, ii = hw >> 3;
  int wid = (xcd < r ? xcd * (q + 1) : r * (q + 1) + (xcd - r) * q) + ii;
  int nbase = (wid & 7) * 128;     // 8 N-panels of 128
  int mbase = (wid >> 3) * 256;    // M-tiles of 256

  int c0 = (int)off[level];
  int count = (int)off[level + 1] - c0;
  if (mbase >= count) return;
  int t = threadIdx.x, wv = t >> 6, lane = t & 63;
  if (t < 256) wle[t] = wl[c0 + min(mbase + t, count - 1)];
  __syncthreads();

  int lr = lane >> 3, p = lane & 7;
  const __hip_bfloat16* aptrA[4];
  const __hip_bfloat16* aptrB[4];
  const __hip_bfloat16* bptr[2];
  #pragma unroll
  for (int c = 0; c < 4; c++) {
    int rc = (wv * 4 + c) * 8 + lr;    // 0..255: A-row this lane stages
    int u = p ^ (rc & 7);
    if (FC1) {
      unsigned e = wle[rc];
      int bidx = e & 511, s1 = (e >> 9) & 63, s2 = (e >> 15) & 63;
      aptrA[c] = Asrc + (((size_t)(bidx << 6) + s1) << 10) + (u << 3);
      aptrB[c] = Asrc + (((size_t)(bidx << 6) + s2) << 10) + (u << 3);
    } else {
      aptrA[c] = Asrc + ((size_t)(mbase + rc) << 10) + (u << 3);
      aptrB[c] = aptrA[c];
    }
  }
  #pragma unroll
  for (int c = 0; c < 2; c++) {
    int rc = (wv * 2 + c) * 8 + lr;    // 0..127: B-row this lane stages
    int u = p ^ (rc & 7);
    bptr[c] = wB + (size_t)(nbase + rc) * KTOT + (u << 3);
  }

  f32x4 acc[4][4];
  #pragma unroll
  for (int i = 0; i < 4; i++)
    #pragma unroll
    for (int j = 0; j < 4; j++) acc[i][j] = (f32x4){0.f, 0.f, 0.f, 0.f};

  int mh = wv >> 1, nh = wv & 1;       // 4M x 2N wave grid

  for (int k0 = 0; k0 < KTOT; k0 += 64) {
    #pragma unroll
    for (int c = 0; c < 4; c++) {
      int ch = wv * 4 + c;             // 0..31 A-chunks (8 rows each)
      const __hip_bfloat16* g =
          (FC1 && k0 >= DIM) ? (aptrB[c] + (k0 - DIM)) : (aptrA[c] + k0);
      gld16(g, &As[ch << 9]);
    }
    #pragma unroll
    for (int c = 0; c < 2; c++) {
      int ch = wv * 2 + c;             // 0..15 B-chunks
      gld16(bptr[c] + k0, &Bs[ch << 9]);
    }
    __syncthreads();
    #pragma unroll
    for (int kc = 0; kc < 2; kc++) {
      short8 a[4], bb[4];
      #pragma unroll
      for (int mi = 0; mi < 4; mi++) {
        int rr = mh * 64 + mi * 16 + (lane & 15);
        int u = (kc * 4 + (lane >> 4)) ^ (rr & 7);
        a[mi] = *(const short8*)&As[rr * 64 + u * 8];
      }
      #pragma unroll
      for (int ni = 0; ni < 4; ni++) {
        int rr = nh * 64 + ni * 16 + (lane & 15);
        int u = (kc * 4 + (lane >> 4)) ^ (rr & 7);
        bb[ni] = *(const short8*)&Bs[rr * 64 + u * 8];
      }
      #pragma unroll
      for (int mi = 0; mi < 4; mi++)
        #pragma unroll
        for (int ni = 0; ni < 4; ni++)
          acc[mi][ni] = __builtin_amdgcn_mfma_f32_16x16x32_bf16(a[mi], bb[ni],
                                                                acc[mi][ni], 0, 0, 0);
    }
    __syncthreads();
  }

  #pragma unroll
  for (int mi = 0; mi < 4; mi++) {
    #pragma unroll
    for (int reg = 0; reg < 4; reg++) {
      int m_loc = mh * 64 + mi * 16 + ((lane >> 4) << 2) + reg;
      int m = mbase + m_loc;
      if (m >= count) continue;
      #pragma unroll
      for (int ni = 0; ni < 4; ni++) {
        int n = nbase + nh * 64 + ni * 16 + (lane & 15);
        float v = acc[mi][ni][reg] + bias[n];
        if (FC1) {
          hbuf[(size_t)m * DIM + n] = __float2bfloat16(fast_tanh(v));
        } else {
          unsigned e = wle[m_loc];
          int bidx = e & 511, d = (e >> 9) & 63;
          tfeats[(((size_t)(bidx << 6) + d) << 10) + n] = __float2bfloat16(fast_tanh(v));
          if (e >> 21) rootfeat[(size_t)bidx * DIM + n] = v;
        }
      }
    }
  }
}

// ---------------------------------------------------------------------------
// K7n (R21): narrow-tile GEMM for levels >= 2. BM=64 x BN=128, BK=64,
// 8 waves, wave-tile 32x32 (2M x 4N). ~24 KB LDS -> 4 blocks/CU; doubles
// active blocks vs 128^2 (l=2: 512->1024) to hide the sparse A-gather
// latency (measured: 128-tile 390 TF @2/CU vs 700 TF @4/CU). Bit-exact:
// same per-element K order (k0 asc, kc 0/1), same intrinsic/operands.
// ---------------------------------------------------------------------------
template <int KTOT, bool FC1>
__global__ __launch_bounds__(512) void k_fcn(const __hip_bfloat16* __restrict__ Asrc,
                                             const __hip_bfloat16* __restrict__ wB,
                                             const float* __restrict__ bias,
                                             const unsigned* __restrict__ wl,
                                             const unsigned* __restrict__ off,
                                             __hip_bfloat16* __restrict__ hbuf,
                                             __hip_bfloat16* __restrict__ tfeats,
                                             float* __restrict__ rootfeat,
                                             int level) {
  __shared__ alignas(16) short As[64 * 64];    // 8 KB
  __shared__ alignas(16) short Bs[128 * 64];   // 16 KB
  __shared__ unsigned wle[64];

  int nwg = (int)gridDim.x;
  int hw = (int)blockIdx.x;
  int q = nwg >> 3, r = nwg & 7;
  int xcd = hw & 7, ii = hw >> 3;
  int wid = (xcd < r ? xcd * (q + 1) : r * (q + 1) + (xcd - r) * q) + ii;
  int nbase = (wid & 7) * 128;     // 8 N-panels of 128
  int mbase = (wid >> 3) * 64;     // M-tiles of 64

  int c0 = (int)off[level];
  int count = (int)off[level + 1] - c0;
  if (mbase >= count) return;
  int t = threadIdx.x, wv = t >> 6, lane = t & 63;
  if (t < 64) wle[t] = wl[c0 + min(mbase + t, count - 1)];
  __syncthreads();

  int lr = lane >> 3, p = lane & 7;
  const __hip_bfloat16* aptrA;
  const __hip_bfloat16* aptrB;
  const __hip_bfloat16* bptr[2];
  {
    int rc = wv * 8 + lr;              // 0..63: A-row this lane stages
    int u = p ^ (rc & 7);
    if (FC1) {
      unsigned e = wle[rc];
      int bidx = e & 511, s1 = (e >> 9) & 63, s2 = (e >> 15) & 63;
      aptrA = Asrc + (((size_t)(bidx << 6) + s1) << 10) + (u << 3);
      aptrB = Asrc + (((size_t)(bidx << 6) + s2) << 10) + (u << 3);
    } else {
      aptrA = Asrc + ((size_t)(mbase + rc) << 10) + (u << 3);
      aptrB = aptrA;
    }
  }
  #pragma unroll
  for (int c = 0; c < 2; c++) {
    int rc = (wv * 2 + c) * 8 + lr;    // 0..127: B-row this lane stages
    int u = p ^ (rc & 7);
    bptr[c] = wB + (size_t)(nbase + rc) * KTOT + (u << 3);
  }

  f32x4 acc[2][2];
  #pragma unroll
  for (int i = 0; i < 2; i++)
    #pragma unroll
    for (int j = 0; j < 2; j++) acc[i][j] = (f32x4){0.f, 0.f, 0.f, 0.f};

  int mh = wv >> 2, nh = wv & 3;       // 2M x 4N wave grid

  for (int k0 = 0; k0 < KTOT; k0 += 64) {
    {
      const __hip_bfloat16* g =
          (FC1 && k0 >= DIM) ? (aptrB + (k0 - DIM)) : (aptrA + k0);
      gld16(g, &As[wv << 9]);          // 8 A-chunks, one per wave
    }
    #pragma unroll
    for (int c = 0; c < 2; c++) {
      int ch = wv * 2 + c;             // 0..15 B-chunks
      gld16(bptr[c] + k0, &Bs[ch << 9]);
    }
    __syncthreads();
    #pragma unroll
    for (int kc = 0; kc < 2; kc++) {
      short8 a[2], bb[2];
      #pragma unroll
      for (int mi = 0; mi < 2; mi++) {
        int rr = mh * 32 + mi * 16 + (lane & 15);
        int u = (kc * 4 + (lane >> 4)) ^ (rr & 7);
        a[mi] = *(const short8*)&As[rr * 64 + u * 8];
      }
      #pragma unroll
      for (int ni = 0; ni < 2; ni++) {
        int rn = nh * 32 + ni * 16 + (lane & 15);
        int u = (kc * 4 + (lane >> 4)) ^ (rn & 7);
        bb[ni] = *(const short8*)&Bs[rn * 64 + u * 8];
      }
      #pragma unroll
      for (int mi = 0; mi < 2; mi++)
        #pragma unroll
        for (int ni = 0; ni < 2; ni++)
          acc[mi][ni] = __builtin_amdgcn_mfma_f32_16x16x32_bf16(a[mi], bb[ni],
                                                                acc[mi][ni], 0, 0, 0);
    }
    __syncthreads();
  }

  #pragma unroll
  for (int mi = 0; mi < 2; mi++) {
    #pragma unroll
    for (int reg = 0; reg < 4; reg++) {
      int m_loc = mh * 32 + mi * 16 + ((lane >> 4) << 2) + reg;
      int m = mbase + m_loc;
      if (m >= count) continue;
      #pragma unroll
      for (int ni = 0; ni < 2; ni++) {
        int n = nbase + nh * 32 + ni * 16 + (lane & 15);
        float v = acc[mi][ni][reg] + bias[n];
        if (FC1) {
          hbuf[(size_t)m * DIM + n] = __float2bfloat16(fast_tanh(v));
        } else {
          unsigned e = wle[m_loc];
          int bidx = e & 511, d = (e >> 9) & 63;
          tfeats[(((size_t)(bidx << 6) + d) << 10) + n] = __float2bfloat16(fast_tanh(v));
          if (e >> 21) rootfeat[(size_t)bidx * DIM + n] = v;
        }
      }
    }
  }
}

// ---------------------------------------------------------------------------
// K7b (R22): deep-level fallback (> LMAX) + fused final scores. One block
// per bag. GEMV restructured to 8-lane output groups: lanes in a group read
// 8 consecutive short8 weight chunks (128B coalesced), xs reads broadcast
// across groups, reduce = 3 shuffles (was: 1 output per 64-lane wave with a
// 6-stage butterfly -> ~80% of cycles in shuffle latency). Feature-path-only
// summation reorder (within bf16/fast_tanh tolerance); nw path untouched.
// ---------------------------------------------------------------------------
#define XP(i) ((i) + ((i) >> 3))
__global__ __launch_bounds__(1024) void k_deep(__hip_bfloat16* __restrict__ tfeats,
                                               const __hip_bfloat16* __restrict__ w1b,
                                               const float* __restrict__ b1,
                                               const __hip_bfloat16* __restrict__ w2b,
                                               const float* __restrict__ b2,
                                               const unsigned* __restrict__ lvlbuf,
                                               float* __restrict__ rootfeat,
                                               const float* __restrict__ rel,
                                               float* __restrict__ out) {
  int b = blockIdx.x;
  __shared__ float xs[XP(2048) + 1];
  __shared__ float hs[XP(1024) + 1];
  __shared__ unsigned steps[NSTEP];
  int t = threadIdx.x, wv = t >> 6, lane = t & 63;
  int og = lane >> 3, ol = lane & 7;   // 8 output-groups of 8 lanes per wave
  if (t < NSTEP) steps[t] = lvlbuf[b * NSTEP + t];
  __syncthreads();

  for (int s = 0; s < NSTEP; s++) {
    unsigned e = steps[s];
    int lvl = (int)((e >> 12) & 63);
    if (lvl <= LMAX) continue;
    int i1 = (int)(e & 63), i2 = (int)((e >> 6) & 63);
    const __hip_bfloat16* r1 = tfeats + ((((size_t)b << 6) + i1) << 10);
    const __hip_bfloat16* r2 = tfeats + ((((size_t)b << 6) + i2) << 10);
    xs[XP(t)] = __bfloat162float(r1[t]);
    xs[XP(1024 + t)] = __bfloat162float(r2[t]);
    __syncthreads();
    // FC1: wave owns n in [wv*64, wv*64+64); 8 outputs per round, 8 rounds.
    #pragma unroll
    for (int r8 = 0; r8 < 8; r8++) {
      int n = wv * 64 + r8 * 8 + og;
      const short8* wr = (const short8*)(w1b + (size_t)n * 2048);
      float acc = 0.f;
      #pragma unroll 4
      for (int it = 0; it < 32; it++) {
        int c = it * 8 + ol;
        short8 w8 = wr[c];
        #pragma unroll
        for (int j = 0; j < 8; j++) {
          float wf = __uint_as_float(((unsigned)(unsigned short)w8[j]) << 16);
          acc += xs[XP(c * 8 + j)] * wf;
        }
      }
      acc += __shfl_xor(acc, 1);
      acc += __shfl_xor(acc, 2);
      acc += __shfl_xor(acc, 4);
      if (ol == 0) hs[XP(n)] = fast_tanh(acc + b1[n]);
    }
    __syncthreads();
    // FC2: same structure, K=1024 (16 chunk-iters).
    #pragma unroll
    for (int r8 = 0; r8 < 8; r8++) {
      int n = wv * 64 + r8 * 8 + og;
      const short8* wr = (const short8*)(w2b + (size_t)n * 1024);
      float acc = 0.f;
      #pragma unroll 4
      for (int it = 0; it < 16; it++) {
        int c = it * 8 + ol;
        short8 w8 = wr[c];
        #pragma unroll
        for (int j = 0; j < 8; j++) {
          float wf = __uint_as_float(((unsigned)(unsigned short)w8[j]) << 16);
          acc += hs[XP(c * 8 + j)] * wf;
        }
      }
      acc += __shfl_xor(acc, 1);
      acc += __shfl_xor(acc, 2);
      acc += __shfl_xor(acc, 4);
      if (ol == 0) {
        float f = acc + b2[n];
        tfeats[((((size_t)b << 6) + i1) << 10) + n] = __float2bfloat16(fast_tanh(f));
        if (s == NSTEP - 1) rootfeat[(size_t)b * DIM + n] = f;
      }
    }
    __syncthreads();
  }

  // ---- fused scores: sigmoid(rootfeat[b] @ rel^T)
  __shared__ float fr[DIM];
  fr[t] = rootfeat[(size_t)b * DIM + t];
  __syncthreads();
  for (int c = wv; c < NCLS; c += 16) {
    const float* w = rel + (size_t)c * DIM;
    float acc = 0.f;
    for (int jx = lane; jx < DIM; jx += 64) acc += fr[jx] * w[jx];
    for (int off = 32; off; off >>= 1) acc += __shfl_xor(acc, off);
    if (lane == 0) out[b * NCLS + c] = 1.0f / (1.0f + expf(-acc));
  }
}

// ---------------------------------------------------------------------------
extern "C" void kernel_launch(void* const* d_in, const int* in_sizes, int n_in,
                              void* d_out, int out_size, void* d_ws, size_t ws_size,
                              hipStream_t stream) {
  const float* rep = (const float*)d_in[0];
  const float* w1  = (const float*)d_in[1];
  const float* b1  = (const float*)d_in[2];
  const float* w2  = (const float*)d_in[3];
  const float* b2  = (const float*)d_in[4];
  const float* rel = (const float*)d_in[5];
  float* out = (float*)d_out;

  char* ws = (char*)d_ws;
  __hip_bfloat16* tfeats = (__hip_bfloat16*)ws; ws += (size_t)NBAG * NPB * DIM * 2;
  __hip_bfloat16* hbuf   = (__hip_bfloat16*)ws; ws += (size_t)MAXROWS * DIM * 2;
  __hip_bfloat16* w1b    = (__hip_bfloat16*)ws; ws += (size_t)DIM * 2 * DIM * 2;
  __hip_bfloat16* w2b    = (__hip_bfloat16*)ws; ws += (size_t)DIM * DIM * 2;
  float* rootfeat        = (float*)ws;          ws += (size_t)NBAG * DIM * 4;
  float* nw              = (float*)ws;          ws += (size_t)NBAG * NPB * 4;
  float* inv_g           = (float*)ws;          ws += (size_t)NBAG * NPB * 4;
  unsigned* lvlbuf       = (unsigned*)ws;       ws += (size_t)NBAG * NSTEP * 4;
  unsigned* cnt          = (unsigned*)ws;       ws += (size_t)NBAG * 64 * 4;
  unsigned* bagoff       = (unsigned*)ws;       ws += (size_t)64 * 512 * 4;
  unsigned* levtot       = (unsigned*)ws;       ws += 64 * 4;
  unsigned* off          = (unsigned*)ws;       ws += 128 * 4;
  unsigned* wl           = (unsigned*)ws;       ws += (size_t)NBAG * NSTEP * 4;

  k_prep_a<<<NBAG * 4, 256, 0, stream>>>(rep, inv_g, tfeats, w1, w1b, w2, w2b);
  k_prep_b<<<NBAG, 1024, 0, stream>>>(rep, inv_g, nw);
  k_merge_levels<<<NBAG / 4, 256, 0, stream>>>(nw, lvlbuf, cnt);
  k_bagscan<<<63, 512, 0, stream>>>(cnt, bagoff, levtot);
  k_scatter<<<126, 256, 0, stream>>>(lvlbuf, levtot, bagoff, wl, off);

  // level 1: wide 256x128 tiles (grid 512 = 2/CU; measured 890 TF)
  k_fcw<2 * DIM, true><<<dim3(8 * 64), 512, 0, stream>>>(
      tfeats, w1b, b1, wl, off, hbuf, nullptr, nullptr, 1);
  k_fcw<DIM, false><<<dim3(8 * 64), 512, 0, stream>>>(
      hbuf, w2b, b2, wl, off, nullptr, tfeats, rootfeat, 1);

  // levels 2..LMAX: narrow 64x128 tiles (2x blocks vs 128^2 -> 4 blocks/CU)
  for (int l = 2; l <= LMAX; l++) {
    int cap = 64 / (l + 1); if (cap > 32) cap = 32;
    int capM = 8 * cap;                       // 64-row M-tiles capacity
    k_fcn<2 * DIM, true><<<dim3(8 * capM), 512, 0, stream>>>(
        tfeats, w1b, b1, wl, off, hbuf, nullptr, nullptr, l);
    k_fcn<DIM, false><<<dim3(8 * capM), 512, 0, stream>>>(
        hbuf, w2b, b2, wl, off, nullptr, tfeats, rootfeat, l);
  }
  k_deep<<<NBAG, 1024, 0, stream>>>(tfeats, w1b, b1, w2b, b2, lvlbuf, rootfeat,
                                    rel, out);
}

// Round 12
// 612.912 us; speedup vs baseline: 1.0202x; 1.0202x over previous
//
#include <hip/hip_runtime.h>
#include <hip/hip_bf16.h>
#include <math.h>

#define NBAG 512
#define NPB 64
#define DIM 1024
#define NCLS 53
#define NSTEP 63
#define MAXROWS 16384  // level-1 worst case: 512 bags * 32 merges
#define LMAX 8         // levels 1..LMAX via batched GEMM; deeper via k_deep
                       // (R20/R21 tile ladder: 256x128 k_fcw @ l=1 (890 TF at 512
                       //  blocks); 64x128 k_fcn @ l>=2 (gather-latency levels need
                       //  block-count: 128-tile measured 390 TF @2/CU vs 700 @4/CU).
                       //  All variants bit-exact: same per-element K order.
                       //  R22 k_deep 8-lane-group GEMV REVERTED: +15us — rounds are
                       //  independent so ILP already hid the butterfly; the change
                       //  only degraded weight-read coalescing (1KB -> 8x128B).)

typedef __attribute__((ext_vector_type(8))) short short8;
typedef __attribute__((ext_vector_type(4))) short short4v;
typedef __attribute__((ext_vector_type(4))) float f32x4;
typedef unsigned long long u64;

__device__ __forceinline__ short bf16bits(float x) {
  __hip_bfloat16 h = __float2bfloat16(x);
  return *reinterpret_cast<short*>(&h);
}

// fast tanh: 1 - 2/(e^{2x}+1). Feature path only — never in the node-weight
// computation (tree order must not change).
__device__ __forceinline__ float fast_tanh(float x) {
  float e = __expf(2.0f * x);
  return 1.0f - __fdividef(2.0f, e + 1.0f);
}

// global -> LDS direct copy, 16B per lane, dest = wave-uniform base + lane*16
__device__ __forceinline__ void gld16(const void* g, void* l) {
  __builtin_amdgcn_global_load_lds(
      (const __attribute__((address_space(1))) void*)g,
      (__attribute__((address_space(3))) void*)(unsigned)(uintptr_t)l,
      16, 0, 0);
}

// ---------------------------------------------------------------------------
// K1a (R15): row-parallel norms + tanh leaves + weight tail. 4 blocks/bag,
// 16 rows each -> 2048 blocks (8/CU). Bitwise-identical per-row reductions.
// ---------------------------------------------------------------------------
__global__ __launch_bounds__(256) void k_prep_a(const float* __restrict__ rep,
                                                float* __restrict__ inv_g,
                                                __hip_bfloat16* __restrict__ tfeats,
                                                const float* __restrict__ w1,
                                                __hip_bfloat16* __restrict__ w1b,
                                                const float* __restrict__ w2,
                                                __hip_bfloat16* __restrict__ w2b) {
  int blk = blockIdx.x;
  int b = blk >> 2, qr = blk & 3;
  const float* bag = rep + (size_t)b * NPB * DIM;
  int t = threadIdx.x, wave = t >> 6, lane = t & 63;

  #pragma unroll
  for (int r = 0; r < 4; r++) {
    int n = qr * 16 + wave * 4 + r;
    const float* x = bag + (size_t)n * DIM;
    float f[16];
    #pragma unroll
    for (int k = 0; k < 16; k++) f[k] = x[lane + 64 * k];
    float acc = 0.f;
    #pragma unroll
    for (int k = 0; k < 16; k++) acc += f[k] * f[k];
    __hip_bfloat16* tr = tfeats + ((((size_t)b << 6) + n) << 10);
    #pragma unroll
    for (int k = 0; k < 16; k++) {
      short o = bf16bits(fast_tanh(f[k]));
      tr[lane + 64 * k] = *reinterpret_cast<__hip_bfloat16*>(&o);
    }
    for (int off = 32; off; off >>= 1) acc += __shfl_xor(acc, off);
    if (lane == 0) inv_g[b * 64 + n] = 1.0f / sqrtf(acc);
  }

  // ---- fused weight conversion tail (elementwise -> mapping-independent)
  {
    const int nv1 = (DIM * 2 * DIM) / 4;
    const int nv2 = (DIM * DIM) / 4;
    for (int i = blk * 256 + t; i < nv1 + nv2; i += 2048 * 256) {
      if (i < nv1) {
        f32x4 v = ((const f32x4*)w1)[i];
        short4v o;
        o.x = bf16bits(v.x); o.y = bf16bits(v.y);
        o.z = bf16bits(v.z); o.w = bf16bits(v.w);
        ((short4v*)w1b)[i] = o;
      } else {
        f32x4 v = ((const f32x4*)w2)[i - nv1];
        short4v o;
        o.x = bf16bits(v.x); o.y = bf16bits(v.y);
        o.z = bf16bits(v.z); o.w = bf16bits(v.w);
        ((short4v*)w2b)[i - nv1] = o;
      }
    }
  }
}

// ---------------------------------------------------------------------------
// K1b (R15): per-bag S (pass 2), dist (pass 3), softmax -> nw. Exact proven
// summation orders; inv_n from k_prep_a via global.
// ---------------------------------------------------------------------------
__global__ __launch_bounds__(1024) void k_prep_b(const float* __restrict__ rep,
                                                 const float* __restrict__ inv_g,
                                                 float* __restrict__ nw) {
  int b = blockIdx.x;
  const float* bag = rep + (size_t)b * NPB * DIM;
  __shared__ float inv_n[NPB];
  __shared__ float dist[NPB];
  __shared__ alignas(16) float S[DIM];
  int t = threadIdx.x, wave = t >> 6, lane = t & 63;

  if (t < 64) inv_n[t] = inv_g[b * 64 + t];
  __syncthreads();

  // ---- pass 2: S, vectorized across columns; per-column n-order unchanged
  if (t < 256) {
    const f32x4* br = (const f32x4*)bag;
    f32x4 acc = (f32x4){0.f, 0.f, 0.f, 0.f};
    #pragma unroll 16
    for (int n = 0; n < NPB; n++) {
      f32x4 v = br[n * 256 + t];
      float w = inv_n[n];
      acc.x += v.x * w; acc.y += v.y * w;
      acc.z += v.z * w; acc.w += v.w * w;
    }
    ((f32x4*)S)[t] = acc;
  }
  __syncthreads();

  // ---- pass 3: dist, strided scalar loads, exact-order dot with S
  for (int n = wave; n < NPB; n += 16) {
    const float* x = bag + (size_t)n * DIM;
    float f[16];
    #pragma unroll
    for (int k = 0; k < 16; k++) f[k] = x[lane + 64 * k];
    float acc = 0.f;
    #pragma unroll
    for (int k = 0; k < 16; k++) acc += f[k] * S[lane + 64 * k];
    for (int off = 32; off; off >>= 1) acc += __shfl_xor(acc, off);
    if (lane == 0) dist[n] = acc * inv_n[n];
  }
  __syncthreads();

  if (t < 64) {
    float v = dist[t], m = v;
    for (int off = 32; off; off >>= 1) m = fmaxf(m, __shfl_xor(m, off));
    float e = expf(v - m), s = e;
    for (int off = 32; off; off >>= 1) s += __shfl_xor(s, off);
    nw[b * NPB + t] = e / s;
  }
}

// ---------------------------------------------------------------------------
// K2 (R16): packed-key two-smallest butterfly Huffman. Bit-exact.
// ---------------------------------------------------------------------------
__global__ __launch_bounds__(256) void k_merge_levels(const float* __restrict__ nw,
                                                      unsigned* __restrict__ lvlbuf,
                                                      unsigned* __restrict__ cnt) {
  int b = blockIdx.x * 4 + (threadIdx.x >> 6);
  int lane = threadIdx.x & 63;
  float w = nw[b * NPB + lane];
  bool alive = true;
  int ready = 0;
  int mycnt = 0;

  for (int t = 0; t < NSTEP; t++) {
    u64 k1 = alive ? (((u64)__float_as_uint(w) << 32) |
                      ((unsigned)lane << 6) | (unsigned)ready)
                   : ~0ull;
    u64 k2 = ~0ull;
    #pragma unroll
    for (int off = 32; off; off >>= 1) {
      u64 o1 = __shfl_xor(k1, off);
      u64 o2 = __shfl_xor(k2, off);
      if (o1 < k1) {
        k2 = (k1 < o2) ? k1 : o2;
        k1 = o1;
      } else {
        k2 = (o1 < k2) ? o1 : k2;
      }
    }
    int i1 = (int)(k1 >> 6) & 63;
    int i2 = (int)(k2 >> 6) & 63;
    float w1v = __uint_as_float((unsigned)(k1 >> 32));
    float w2v = __uint_as_float((unsigned)(k2 >> 32));
    int r1 = (int)(k1 & 63u);
    int r2 = (int)(k2 & 63u);
    int lvl = max(r1, r2) + 1;
    int rank = __shfl(mycnt, lvl - 1);
    if (lane == lvl - 1) mycnt++;
    if (lane == i1) { w = w1v + w2v; ready = lvl; }
    if (lane == i2) alive = false;
    if (lane == 0)
      lvlbuf[b * NSTEP + t] = (unsigned)i1 | ((unsigned)i2 << 6) |
                              ((unsigned)lvl << 12) | ((unsigned)rank << 18);
  }
  cnt[b * 64 + lane] = (unsigned)mycnt;
}

// K3: per-level exclusive scan over bags
__global__ __launch_bounds__(512) void k_bagscan(const unsigned* __restrict__ cnt,
                                                 unsigned* __restrict__ bagoff,
                                                 unsigned* __restrict__ levtot) {
  int l = blockIdx.x + 1;
  int b = threadIdx.x;
  __shared__ unsigned s[512];
  unsigned v = cnt[b * 64 + (l - 1)];
  s[b] = v; __syncthreads();
  for (int o = 1; o < 512; o <<= 1) {
    unsigned x = (b >= o) ? s[b - o] : 0u; __syncthreads();
    s[b] += x; __syncthreads();
  }
  bagoff[l * 512 + b] = s[b] - v;
  if (b == 511) levtot[l] = s[511];
}

// K5: scatter merges into level-sorted worklist (fused level-offset scan).
__global__ __launch_bounds__(256) void k_scatter(const unsigned* __restrict__ lvlbuf,
                                                 const unsigned* __restrict__ levtot,
                                                 const unsigned* __restrict__ bagoff,
                                                 unsigned* __restrict__ wl,
                                                 unsigned* __restrict__ off_out) {
  __shared__ unsigned off_s[65];
  int t = threadIdx.x;
  if (t < 64) {
    unsigned v = (t >= 1) ? levtot[t] : 0u;
    unsigned x = v;
    for (int o = 1; o < 64; o <<= 1) {
      unsigned y = __shfl_up(x, o);
      if (t >= o) x += y;
    }
    off_s[t] = x - v;
    if (t == 63) off_s[64] = x;
    if (blockIdx.x == 0) {
      off_out[t] = x - v;
      if (t == 63) off_out[64] = x;
    }
  }
  __syncthreads();

  int idx = blockIdx.x * 256 + t;
  int b = idx / NSTEP, st = idx % NSTEP;
  unsigned e = lvlbuf[idx];
  unsigned i1 = e & 63, i2 = (e >> 6) & 63, lvl = (e >> 12) & 63, rank = (e >> 18) & 31;
  unsigned pos = off_s[lvl] + bagoff[lvl * 512 + b] + rank;
  wl[pos] = (unsigned)b | (i1 << 9) | (i2 << 15) | ((st == NSTEP - 1 ? 1u : 0u) << 21);
}

// ---------------------------------------------------------------------------
// K7w (R20): wide-tile GEMM for level 1 (full-GPU grid). BM=256 x BN=128,
// BK=64, 8 waves, wave-tile 64x64 (4M x 2N). Proven R11/R18 body verbatim
// (bit-exact outputs). Measured 78us (890 TF) at the l=1 grid.
// ---------------------------------------------------------------------------
template <int KTOT, bool FC1>
__global__ __launch_bounds__(512) void k_fcw(const __hip_bfloat16* __restrict__ Asrc,
                                             const __hip_bfloat16* __restrict__ wB,
                                             const float* __restrict__ bias,
                                             const unsigned* __restrict__ wl,
                                             const unsigned* __restrict__ off,
                                             __hip_bfloat16* __restrict__ hbuf,
                                             __hip_bfloat16* __restrict__ tfeats,
                                             float* __restrict__ rootfeat,
                                             int level) {
  __shared__ alignas(16) short As[256 * 64];   // 32 KB
  __shared__ alignas(16) short Bs[128 * 64];   // 16 KB
  __shared__ unsigned wle[256];

  int nwg = (int)gridDim.x;
  int hw = (int)blockIdx.x;
  int q = nwg >> 3, r = nwg & 7;
  int xcd = hw & 7, ii = hw >> 3;
  int wid = (xcd < r ? xcd * (q + 1) : r * (q + 1) + (xcd - r) * q) + ii;
  int nbase = (wid & 7) * 128;     // 8 N-panels of 128
  int mbase = (wid >> 3) * 256;    // M-tiles of 256

  int c0 = (int)off[level];
  int count = (int)off[level + 1] - c0;
  if (mbase >= count) return;
  int t = threadIdx.x, wv = t >> 6, lane = t & 63;
  if (t < 256) wle[t] = wl[c0 + min(mbase + t, count - 1)];
  __syncthreads();

  int lr = lane >> 3, p = lane & 7;
  const __hip_bfloat16* aptrA[4];
  const __hip_bfloat16* aptrB[4];
  const __hip_bfloat16* bptr[2];
  #pragma unroll
  for (int c = 0; c < 4; c++) {
    int rc = (wv * 4 + c) * 8 + lr;    // 0..255: A-row this lane stages
    int u = p ^ (rc & 7);
    if (FC1) {
      unsigned e = wle[rc];
      int bidx = e & 511, s1 = (e >> 9) & 63, s2 = (e >> 15) & 63;
      aptrA[c] = Asrc + (((size_t)(bidx << 6) + s1) << 10) + (u << 3);
      aptrB[c] = Asrc + (((size_t)(bidx << 6) + s2) << 10) + (u << 3);
    } else {
      aptrA[c] = Asrc + ((size_t)(mbase + rc) << 10) + (u << 3);
      aptrB[c] = aptrA[c];
    }
  }
  #pragma unroll
  for (int c = 0; c < 2; c++) {
    int rc = (wv * 2 + c) * 8 + lr;    // 0..127: B-row this lane stages
    int u = p ^ (rc & 7);
    bptr[c] = wB + (size_t)(nbase + rc) * KTOT + (u << 3);
  }

  f32x4 acc[4][4];
  #pragma unroll
  for (int i = 0; i < 4; i++)
    #pragma unroll
    for (int j = 0; j < 4; j++) acc[i][j] = (f32x4){0.f, 0.f, 0.f, 0.f};

  int mh = wv >> 1, nh = wv & 1;       // 4M x 2N wave grid

  for (int k0 = 0; k0 < KTOT; k0 += 64) {
    #pragma unroll
    for (int c = 0; c < 4; c++) {
      int ch = wv * 4 + c;             // 0..31 A-chunks (8 rows each)
      const __hip_bfloat16* g =
          (FC1 && k0 >= DIM) ? (aptrB[c] + (k0 - DIM)) : (aptrA[c] + k0);
      gld16(g, &As[ch << 9]);
    }
    #pragma unroll
    for (int c = 0; c < 2; c++) {
      int ch = wv * 2 + c;             // 0..15 B-chunks
      gld16(bptr[c] + k0, &Bs[ch << 9]);
    }
    __syncthreads();
    #pragma unroll
    for (int kc = 0; kc < 2; kc++) {
      short8 a[4], bb[4];
      #pragma unroll
      for (int mi = 0; mi < 4; mi++) {
        int rr = mh * 64 + mi * 16 + (lane & 15);
        int u = (kc * 4 + (lane >> 4)) ^ (rr & 7);
        a[mi] = *(const short8*)&As[rr * 64 + u * 8];
      }
      #pragma unroll
      for (int ni = 0; ni < 4; ni++) {
        int rr = nh * 64 + ni * 16 + (lane & 15);
        int u = (kc * 4 + (lane >> 4)) ^ (rr & 7);
        bb[ni] = *(const short8*)&Bs[rr * 64 + u * 8];
      }
      #pragma unroll
      for (int mi = 0; mi < 4; mi++)
        #pragma unroll
        for (int ni = 0; ni < 4; ni++)
          acc[mi][ni] = __builtin_amdgcn_mfma_f32_16x16x32_bf16(a[mi], bb[ni],
                                                                acc[mi][ni], 0, 0, 0);
    }
    __syncthreads();
  }

  #pragma unroll
  for (int mi = 0; mi < 4; mi++) {
    #pragma unroll
    for (int reg = 0; reg < 4; reg++) {
      int m_loc = mh * 64 + mi * 16 + ((lane >> 4) << 2) + reg;
      int m = mbase + m_loc;
      if (m >= count) continue;
      #pragma unroll
      for (int ni = 0; ni < 4; ni++) {
        int n = nbase + nh * 64 + ni * 16 + (lane & 15);
        float v = acc[mi][ni][reg] + bias[n];
        if (FC1) {
          hbuf[(size_t)m * DIM + n] = __float2bfloat16(fast_tanh(v));
        } else {
          unsigned e = wle[m_loc];
          int bidx = e & 511, d = (e >> 9) & 63;
          tfeats[(((size_t)(bidx << 6) + d) << 10) + n] = __float2bfloat16(fast_tanh(v));
          if (e >> 21) rootfeat[(size_t)bidx * DIM + n] = v;
        }
      }
    }
  }
}

// ---------------------------------------------------------------------------
// K7n (R21): narrow-tile GEMM for levels >= 2. BM=64 x BN=128, BK=64,
// 8 waves, wave-tile 32x32 (2M x 4N). ~24 KB LDS -> 4 blocks/CU; doubles
// active blocks vs 128^2 (l=2: 512->1024) to hide the sparse A-gather
// latency (measured: 128-tile 390 TF @2/CU vs 700 TF @4/CU). Bit-exact:
// same per-element K order (k0 asc, kc 0/1), same intrinsic/operands.
// ---------------------------------------------------------------------------
template <int KTOT, bool FC1>
__global__ __launch_bounds__(512) void k_fcn(const __hip_bfloat16* __restrict__ Asrc,
                                             const __hip_bfloat16* __restrict__ wB,
                                             const float* __restrict__ bias,
                                             const unsigned* __restrict__ wl,
                                             const unsigned* __restrict__ off,
                                             __hip_bfloat16* __restrict__ hbuf,
                                             __hip_bfloat16* __restrict__ tfeats,
                                             float* __restrict__ rootfeat,
                                             int level) {
  __shared__ alignas(16) short As[64 * 64];    // 8 KB
  __shared__ alignas(16) short Bs[128 * 64];   // 16 KB
  __shared__ unsigned wle[64];

  int nwg = (int)gridDim.x;
  int hw = (int)blockIdx.x;
  int q = nwg >> 3, r = nwg & 7;
  int xcd = hw & 7, ii = hw >> 3;
  int wid = (xcd < r ? xcd * (q + 1) : r * (q + 1) + (xcd - r) * q) + ii;
  int nbase = (wid & 7) * 128;     // 8 N-panels of 128
  int mbase = (wid >> 3) * 64;     // M-tiles of 64

  int c0 = (int)off[level];
  int count = (int)off[level + 1] - c0;
  if (mbase >= count) return;
  int t = threadIdx.x, wv = t >> 6, lane = t & 63;
  if (t < 64) wle[t] = wl[c0 + min(mbase + t, count - 1)];
  __syncthreads();

  int lr = lane >> 3, p = lane & 7;
  const __hip_bfloat16* aptrA;
  const __hip_bfloat16* aptrB;
  const __hip_bfloat16* bptr[2];
  {
    int rc = wv * 8 + lr;              // 0..63: A-row this lane stages
    int u = p ^ (rc & 7);
    if (FC1) {
      unsigned e = wle[rc];
      int bidx = e & 511, s1 = (e >> 9) & 63, s2 = (e >> 15) & 63;
      aptrA = Asrc + (((size_t)(bidx << 6) + s1) << 10) + (u << 3);
      aptrB = Asrc + (((size_t)(bidx << 6) + s2) << 10) + (u << 3);
    } else {
      aptrA = Asrc + ((size_t)(mbase + rc) << 10) + (u << 3);
      aptrB = aptrA;
    }
  }
  #pragma unroll
  for (int c = 0; c < 2; c++) {
    int rc = (wv * 2 + c) * 8 + lr;    // 0..127: B-row this lane stages
    int u = p ^ (rc & 7);
    bptr[c] = wB + (size_t)(nbase + rc) * KTOT + (u << 3);
  }

  f32x4 acc[2][2];
  #pragma unroll
  for (int i = 0; i < 2; i++)
    #pragma unroll
    for (int j = 0; j < 2; j++) acc[i][j] = (f32x4){0.f, 0.f, 0.f, 0.f};

  int mh = wv >> 2, nh = wv & 3;       // 2M x 4N wave grid

  for (int k0 = 0; k0 < KTOT; k0 += 64) {
    {
      const __hip_bfloat16* g =
          (FC1 && k0 >= DIM) ? (aptrB + (k0 - DIM)) : (aptrA + k0);
      gld16(g, &As[wv << 9]);          // 8 A-chunks, one per wave
    }
    #pragma unroll
    for (int c = 0; c < 2; c++) {
      int ch = wv * 2 + c;             // 0..15 B-chunks
      gld16(bptr[c] + k0, &Bs[ch << 9]);
    }
    __syncthreads();
    #pragma unroll
    for (int kc = 0; kc < 2; kc++) {
      short8 a[2], bb[2];
      #pragma unroll
      for (int mi = 0; mi < 2; mi++) {
        int rr = mh * 32 + mi * 16 + (lane & 15);
        int u = (kc * 4 + (lane >> 4)) ^ (rr & 7);
        a[mi] = *(const short8*)&As[rr * 64 + u * 8];
      }
      #pragma unroll
      for (int ni = 0; ni < 2; ni++) {
        int rn = nh * 32 + ni * 16 + (lane & 15);
        int u = (kc * 4 + (lane >> 4)) ^ (rn & 7);
        bb[ni] = *(const short8*)&Bs[rn * 64 + u * 8];
      }
      #pragma unroll
      for (int mi = 0; mi < 2; mi++)
        #pragma unroll
        for (int ni = 0; ni < 2; ni++)
          acc[mi][ni] = __builtin_amdgcn_mfma_f32_16x16x32_bf16(a[mi], bb[ni],
                                                                acc[mi][ni], 0, 0, 0);
    }
    __syncthreads();
  }

  #pragma unroll
  for (int mi = 0; mi < 2; mi++) {
    #pragma unroll
    for (int reg = 0; reg < 4; reg++) {
      int m_loc = mh * 32 + mi * 16 + ((lane >> 4) << 2) + reg;
      int m = mbase + m_loc;
      if (m >= count) continue;
      #pragma unroll
      for (int ni = 0; ni < 2; ni++) {
        int n = nbase + nh * 32 + ni * 16 + (lane & 15);
        float v = acc[mi][ni][reg] + bias[n];
        if (FC1) {
          hbuf[(size_t)m * DIM + n] = __float2bfloat16(fast_tanh(v));
        } else {
          unsigned e = wle[m_loc];
          int bidx = e & 511, d = (e >> 9) & 63;
          tfeats[(((size_t)(bidx << 6) + d) << 10) + n] = __float2bfloat16(fast_tanh(v));
          if (e >> 21) rootfeat[(size_t)bidx * DIM + n] = v;
        }
      }
    }
  }
}

// ---------------------------------------------------------------------------
// K7b: deep-level fallback (> LMAX) + fused final scores. One block per bag.
// (R21 proven form; R22's 8-lane-group GEMV reverted — see LMAX note.)
// ---------------------------------------------------------------------------
#define XP(i) ((i) + ((i) >> 3))
__global__ __launch_bounds__(1024) void k_deep(__hip_bfloat16* __restrict__ tfeats,
                                               const __hip_bfloat16* __restrict__ w1b,
                                               const float* __restrict__ b1,
                                               const __hip_bfloat16* __restrict__ w2b,
                                               const float* __restrict__ b2,
                                               const unsigned* __restrict__ lvlbuf,
                                               float* __restrict__ rootfeat,
                                               const float* __restrict__ rel,
                                               float* __restrict__ out) {
  int b = blockIdx.x;
  __shared__ float xs[XP(2048) + 1];
  __shared__ float hs[XP(1024) + 1];
  __shared__ unsigned steps[NSTEP];
  int t = threadIdx.x, wv = t >> 6, lane = t & 63;
  if (t < NSTEP) steps[t] = lvlbuf[b * NSTEP + t];
  __syncthreads();

  for (int s = 0; s < NSTEP; s++) {
    unsigned e = steps[s];
    int lvl = (int)((e >> 12) & 63);
    if (lvl <= LMAX) continue;
    int i1 = (int)(e & 63), i2 = (int)((e >> 6) & 63);
    const __hip_bfloat16* r1 = tfeats + ((((size_t)b << 6) + i1) << 10);
    const __hip_bfloat16* r2 = tfeats + ((((size_t)b << 6) + i2) << 10);
    xs[XP(t)] = __bfloat162float(r1[t]);
    xs[XP(1024 + t)] = __bfloat162float(r2[t]);
    __syncthreads();
    for (int r = 0; r < 64; r++) {
      int n = r * 16 + wv;
      const short8* wr = (const short8*)(w1b + (size_t)n * 2048);
      float acc = 0.f;
      for (int c = lane; c < 256; c += 64) {
        short8 w8 = wr[c];
        #pragma unroll
        for (int j = 0; j < 8; j++) {
          float wf = __uint_as_float(((unsigned)(unsigned short)w8[j]) << 16);
          acc += xs[XP(c * 8 + j)] * wf;
        }
      }
      for (int off = 32; off; off >>= 1) acc += __shfl_xor(acc, off);
      if (lane == 0) hs[XP(n)] = fast_tanh(acc + b1[n]);
    }
    __syncthreads();
    for (int r = 0; r < 64; r++) {
      int n = r * 16 + wv;
      const short8* wr = (const short8*)(w2b + (size_t)n * 1024);
      float acc = 0.f;
      for (int c = lane; c < 128; c += 64) {
        short8 w8 = wr[c];
        #pragma unroll
        for (int j = 0; j < 8; j++) {
          float wf = __uint_as_float(((unsigned)(unsigned short)w8[j]) << 16);
          acc += hs[XP(c * 8 + j)] * wf;
        }
      }
      for (int off = 32; off; off >>= 1) acc += __shfl_xor(acc, off);
      if (lane == 0) {
        float f = acc + b2[n];
        tfeats[((((size_t)b << 6) + i1) << 10) + n] = __float2bfloat16(fast_tanh(f));
        if (s == NSTEP - 1) rootfeat[(size_t)b * DIM + n] = f;
      }
    }
    __syncthreads();
  }

  // ---- fused scores: sigmoid(rootfeat[b] @ rel^T)
  __shared__ float fr[DIM];
  fr[t] = rootfeat[(size_t)b * DIM + t];
  __syncthreads();
  for (int c = wv; c < NCLS; c += 16) {
    const float* w = rel + (size_t)c * DIM;
    float acc = 0.f;
    for (int jx = lane; jx < DIM; jx += 64) acc += fr[jx] * w[jx];
    for (int off = 32; off; off >>= 1) acc += __shfl_xor(acc, off);
    if (lane == 0) out[b * NCLS + c] = 1.0f / (1.0f + expf(-acc));
  }
}

// ---------------------------------------------------------------------------
extern "C" void kernel_launch(void* const* d_in, const int* in_sizes, int n_in,
                              void* d_out, int out_size, void* d_ws, size_t ws_size,
                              hipStream_t stream) {
  const float* rep = (const float*)d_in[0];
  const float* w1  = (const float*)d_in[1];
  const float* b1  = (const float*)d_in[2];
  const float* w2  = (const float*)d_in[3];
  const float* b2  = (const float*)d_in[4];
  const float* rel = (const float*)d_in[5];
  float* out = (float*)d_out;

  char* ws = (char*)d_ws;
  __hip_bfloat16* tfeats = (__hip_bfloat16*)ws; ws += (size_t)NBAG * NPB * DIM * 2;
  __hip_bfloat16* hbuf   = (__hip_bfloat16*)ws; ws += (size_t)MAXROWS * DIM * 2;
  __hip_bfloat16* w1b    = (__hip_bfloat16*)ws; ws += (size_t)DIM * 2 * DIM * 2;
  __hip_bfloat16* w2b    = (__hip_bfloat16*)ws; ws += (size_t)DIM * DIM * 2;
  float* rootfeat        = (float*)ws;          ws += (size_t)NBAG * DIM * 4;
  float* nw              = (float*)ws;          ws += (size_t)NBAG * NPB * 4;
  float* inv_g           = (float*)ws;          ws += (size_t)NBAG * NPB * 4;
  unsigned* lvlbuf       = (unsigned*)ws;       ws += (size_t)NBAG * NSTEP * 4;
  unsigned* cnt          = (unsigned*)ws;       ws += (size_t)NBAG * 64 * 4;
  unsigned* bagoff       = (unsigned*)ws;       ws += (size_t)64 * 512 * 4;
  unsigned* levtot       = (unsigned*)ws;       ws += 64 * 4;
  unsigned* off          = (unsigned*)ws;       ws += 128 * 4;
  unsigned* wl           = (unsigned*)ws;       ws += (size_t)NBAG * NSTEP * 4;

  k_prep_a<<<NBAG * 4, 256, 0, stream>>>(rep, inv_g, tfeats, w1, w1b, w2, w2b);
  k_prep_b<<<NBAG, 1024, 0, stream>>>(rep, inv_g, nw);
  k_merge_levels<<<NBAG / 4, 256, 0, stream>>>(nw, lvlbuf, cnt);
  k_bagscan<<<63, 512, 0, stream>>>(cnt, bagoff, levtot);
  k_scatter<<<126, 256, 0, stream>>>(lvlbuf, levtot, bagoff, wl, off);

  // level 1: wide 256x128 tiles (grid 512 = 2/CU; measured 890 TF)
  k_fcw<2 * DIM, true><<<dim3(8 * 64), 512, 0, stream>>>(
      tfeats, w1b, b1, wl, off, hbuf, nullptr, nullptr, 1);
  k_fcw<DIM, false><<<dim3(8 * 64), 512, 0, stream>>>(
      hbuf, w2b, b2, wl, off, nullptr, tfeats, rootfeat, 1);

  // levels 2..LMAX: narrow 64x128 tiles (2x blocks vs 128^2 -> 4 blocks/CU)
  for (int l = 2; l <= LMAX; l++) {
    int cap = 64 / (l + 1); if (cap > 32) cap = 32;
    int capM = 8 * cap;                       // 64-row M-tiles capacity
    k_fcn<2 * DIM, true><<<dim3(8 * capM), 512, 0, stream>>>(
        tfeats, w1b, b1, wl, off, hbuf, nullptr, nullptr, l);
    k_fcn<DIM, false><<<dim3(8 * capM), 512, 0, stream>>>(
        hbuf, w2b, b2, wl, off, nullptr, tfeats, rootfeat, l);
  }
  k_deep<<<NBAG, 1024, 0, stream>>>(tfeats, w1b, b1, w2b, b2, lvlbuf, rootfeat,
                                    rel, out);
}

// Round 13
// 608.876 us; speedup vs baseline: 1.0269x; 1.0066x over previous
//
#include <hip/hip_runtime.h>
#include <hip/hip_bf16.h>
#include <math.h>

#define NBAG 512
#define NPB 64
#define DIM 1024
#define NCLS 53
#define NSTEP 63
#define MAXROWS 16384  // level-1 worst case: 512 bags * 32 merges
#define LMAX 8         // levels 1..LMAX via batched GEMM; deeper via k_deep
                       // (R20/R21 tile ladder: 256x128 k_fcw @ l=1 (890 TF at 512
                       //  blocks); 64x128 k_fcn @ l>=2 (gather-latency levels need
                       //  block-count: 128-tile measured 390 TF @2/CU vs 700 @4/CU).
                       //  All variants bit-exact: same per-element K order.
                       //  R22 k_deep 8-lane GEMV reverted (+15us, coalescing loss).
                       //  R24: tanh-leaf generation moved prep_a -> prep_b pass 3
                       //  (same registers, bit-exact; saves one 67MB tfeats write
                       //  pass worth of BW on the critical front-end chain).)

typedef __attribute__((ext_vector_type(8))) short short8;
typedef __attribute__((ext_vector_type(4))) short short4v;
typedef __attribute__((ext_vector_type(4))) float f32x4;
typedef unsigned long long u64;

__device__ __forceinline__ short bf16bits(float x) {
  __hip_bfloat16 h = __float2bfloat16(x);
  return *reinterpret_cast<short*>(&h);
}

// fast tanh: 1 - 2/(e^{2x}+1). Feature path only — never in the node-weight
// computation (tree order must not change).
__device__ __forceinline__ float fast_tanh(float x) {
  float e = __expf(2.0f * x);
  return 1.0f - __fdividef(2.0f, e + 1.0f);
}

// global -> LDS direct copy, 16B per lane, dest = wave-uniform base + lane*16
__device__ __forceinline__ void gld16(const void* g, void* l) {
  __builtin_amdgcn_global_load_lds(
      (const __attribute__((address_space(1))) void*)g,
      (__attribute__((address_space(3))) void*)(unsigned)(uintptr_t)l,
      16, 0, 0);
}

// ---------------------------------------------------------------------------
// K1a (R24): row-parallel norms + weight f32->bf16 tail. 4 blocks/bag,
// 16 rows each -> 2048 blocks (8/CU). Norm loop loads/order IDENTICAL to the
// proven R15 form; the tanh-leaf store moved to k_prep_b pass 3 (same f32
// registers there -> tfeats bitwise identical, and this kernel sheds 67MB
// of writes).
// ---------------------------------------------------------------------------
__global__ __launch_bounds__(256) void k_prep_a(const float* __restrict__ rep,
                                                float* __restrict__ inv_g,
                                                const float* __restrict__ w1,
                                                __hip_bfloat16* __restrict__ w1b,
                                                const float* __restrict__ w2,
                                                __hip_bfloat16* __restrict__ w2b) {
  int blk = blockIdx.x;
  int b = blk >> 2, qr = blk & 3;
  const float* bag = rep + (size_t)b * NPB * DIM;
  int t = threadIdx.x, wave = t >> 6, lane = t & 63;

  #pragma unroll
  for (int r = 0; r < 4; r++) {
    int n = qr * 16 + wave * 4 + r;
    const float* x = bag + (size_t)n * DIM;
    float f[16];
    #pragma unroll
    for (int k = 0; k < 16; k++) f[k] = x[lane + 64 * k];
    float acc = 0.f;
    #pragma unroll
    for (int k = 0; k < 16; k++) acc += f[k] * f[k];
    for (int off = 32; off; off >>= 1) acc += __shfl_xor(acc, off);
    if (lane == 0) inv_g[b * 64 + n] = 1.0f / sqrtf(acc);
  }

  // ---- fused weight conversion tail (elementwise -> mapping-independent)
  {
    const int nv1 = (DIM * 2 * DIM) / 4;
    const int nv2 = (DIM * DIM) / 4;
    for (int i = blk * 256 + t; i < nv1 + nv2; i += 2048 * 256) {
      if (i < nv1) {
        f32x4 v = ((const f32x4*)w1)[i];
        short4v o;
        o.x = bf16bits(v.x); o.y = bf16bits(v.y);
        o.z = bf16bits(v.z); o.w = bf16bits(v.w);
        ((short4v*)w1b)[i] = o;
      } else {
        f32x4 v = ((const f32x4*)w2)[i - nv1];
        short4v o;
        o.x = bf16bits(v.x); o.y = bf16bits(v.y);
        o.z = bf16bits(v.z); o.w = bf16bits(v.w);
        ((short4v*)w2b)[i - nv1] = o;
      }
    }
  }
}

// ---------------------------------------------------------------------------
// K1b (R24): per-bag S (pass 2), dist (pass 3) + fused tanh leaves, softmax.
// Pass-3 rows are already in registers for the dist dot; the tanh+bf16 store
// is appended AFTER the dot accumulation (stores are side-effects -> nw
// arithmetic orders unchanged, bitwise identical). inv_n from k_prep_a.
// ---------------------------------------------------------------------------
__global__ __launch_bounds__(1024) void k_prep_b(const float* __restrict__ rep,
                                                 const float* __restrict__ inv_g,
                                                 float* __restrict__ nw,
                                                 __hip_bfloat16* __restrict__ tfeats) {
  int b = blockIdx.x;
  const float* bag = rep + (size_t)b * NPB * DIM;
  __shared__ float inv_n[NPB];
  __shared__ float dist[NPB];
  __shared__ alignas(16) float S[DIM];
  int t = threadIdx.x, wave = t >> 6, lane = t & 63;

  if (t < 64) inv_n[t] = inv_g[b * 64 + t];
  __syncthreads();

  // ---- pass 2: S, vectorized across columns; per-column n-order unchanged
  if (t < 256) {
    const f32x4* br = (const f32x4*)bag;
    f32x4 acc = (f32x4){0.f, 0.f, 0.f, 0.f};
    #pragma unroll 16
    for (int n = 0; n < NPB; n++) {
      f32x4 v = br[n * 256 + t];
      float w = inv_n[n];
      acc.x += v.x * w; acc.y += v.y * w;
      acc.z += v.z * w; acc.w += v.w * w;
    }
    ((f32x4*)S)[t] = acc;
  }
  __syncthreads();

  // ---- pass 3: dist (exact-order dot with S) + tanh leaves from same regs
  for (int n = wave; n < NPB; n += 16) {
    const float* x = bag + (size_t)n * DIM;
    float f[16];
    #pragma unroll
    for (int k = 0; k < 16; k++) f[k] = x[lane + 64 * k];
    float acc = 0.f;
    #pragma unroll
    for (int k = 0; k < 16; k++) acc += f[k] * S[lane + 64 * k];
    __hip_bfloat16* tr = tfeats + ((((size_t)b << 6) + n) << 10);
    #pragma unroll
    for (int k = 0; k < 16; k++) {
      short o = bf16bits(fast_tanh(f[k]));
      tr[lane + 64 * k] = *reinterpret_cast<__hip_bfloat16*>(&o);
    }
    for (int off = 32; off; off >>= 1) acc += __shfl_xor(acc, off);
    if (lane == 0) dist[n] = acc * inv_n[n];
  }
  __syncthreads();

  if (t < 64) {
    float v = dist[t], m = v;
    for (int off = 32; off; off >>= 1) m = fmaxf(m, __shfl_xor(m, off));
    float e = expf(v - m), s = e;
    for (int off = 32; off; off >>= 1) s += __shfl_xor(s, off);
    nw[b * NPB + t] = e / s;
  }
}

// ---------------------------------------------------------------------------
// K2 (R16): packed-key two-smallest butterfly Huffman. Bit-exact.
// ---------------------------------------------------------------------------
__global__ __launch_bounds__(256) void k_merge_levels(const float* __restrict__ nw,
                                                      unsigned* __restrict__ lvlbuf,
                                                      unsigned* __restrict__ cnt) {
  int b = blockIdx.x * 4 + (threadIdx.x >> 6);
  int lane = threadIdx.x & 63;
  float w = nw[b * NPB + lane];
  bool alive = true;
  int ready = 0;
  int mycnt = 0;

  for (int t = 0; t < NSTEP; t++) {
    u64 k1 = alive ? (((u64)__float_as_uint(w) << 32) |
                      ((unsigned)lane << 6) | (unsigned)ready)
                   : ~0ull;
    u64 k2 = ~0ull;
    #pragma unroll
    for (int off = 32; off; off >>= 1) {
      u64 o1 = __shfl_xor(k1, off);
      u64 o2 = __shfl_xor(k2, off);
      if (o1 < k1) {
        k2 = (k1 < o2) ? k1 : o2;
        k1 = o1;
      } else {
        k2 = (o1 < k2) ? o1 : k2;
      }
    }
    int i1 = (int)(k1 >> 6) & 63;
    int i2 = (int)(k2 >> 6) & 63;
    float w1v = __uint_as_float((unsigned)(k1 >> 32));
    float w2v = __uint_as_float((unsigned)(k2 >> 32));
    int r1 = (int)(k1 & 63u);
    int r2 = (int)(k2 & 63u);
    int lvl = max(r1, r2) + 1;
    int rank = __shfl(mycnt, lvl - 1);
    if (lane == lvl - 1) mycnt++;
    if (lane == i1) { w = w1v + w2v; ready = lvl; }
    if (lane == i2) alive = false;
    if (lane == 0)
      lvlbuf[b * NSTEP + t] = (unsigned)i1 | ((unsigned)i2 << 6) |
                              ((unsigned)lvl << 12) | ((unsigned)rank << 18);
  }
  cnt[b * 64 + lane] = (unsigned)mycnt;
}

// K3: per-level exclusive scan over bags
__global__ __launch_bounds__(512) void k_bagscan(const unsigned* __restrict__ cnt,
                                                 unsigned* __restrict__ bagoff,
                                                 unsigned* __restrict__ levtot) {
  int l = blockIdx.x + 1;
  int b = threadIdx.x;
  __shared__ unsigned s[512];
  unsigned v = cnt[b * 64 + (l - 1)];
  s[b] = v; __syncthreads();
  for (int o = 1; o < 512; o <<= 1) {
    unsigned x = (b >= o) ? s[b - o] : 0u; __syncthreads();
    s[b] += x; __syncthreads();
  }
  bagoff[l * 512 + b] = s[b] - v;
  if (b == 511) levtot[l] = s[511];
}

// K5: scatter merges into level-sorted worklist (fused level-offset scan).
__global__ __launch_bounds__(256) void k_scatter(const unsigned* __restrict__ lvlbuf,
                                                 const unsigned* __restrict__ levtot,
                                                 const unsigned* __restrict__ bagoff,
                                                 unsigned* __restrict__ wl,
                                                 unsigned* __restrict__ off_out) {
  __shared__ unsigned off_s[65];
  int t = threadIdx.x;
  if (t < 64) {
    unsigned v = (t >= 1) ? levtot[t] : 0u;
    unsigned x = v;
    for (int o = 1; o < 64; o <<= 1) {
      unsigned y = __shfl_up(x, o);
      if (t >= o) x += y;
    }
    off_s[t] = x - v;
    if (t == 63) off_s[64] = x;
    if (blockIdx.x == 0) {
      off_out[t] = x - v;
      if (t == 63) off_out[64] = x;
    }
  }
  __syncthreads();

  int idx = blockIdx.x * 256 + t;
  int b = idx / NSTEP, st = idx % NSTEP;
  unsigned e = lvlbuf[idx];
  unsigned i1 = e & 63, i2 = (e >> 6) & 63, lvl = (e >> 12) & 63, rank = (e >> 18) & 31;
  unsigned pos = off_s[lvl] + bagoff[lvl * 512 + b] + rank;
  wl[pos] = (unsigned)b | (i1 << 9) | (i2 << 15) | ((st == NSTEP - 1 ? 1u : 0u) << 21);
}

// ---------------------------------------------------------------------------
// K7w (R20): wide-tile GEMM for level 1 (full-GPU grid). BM=256 x BN=128,
// BK=64, 8 waves, wave-tile 64x64 (4M x 2N). Proven R11/R18 body verbatim
// (bit-exact outputs). Measured 78us (890 TF) at the l=1 grid.
// ---------------------------------------------------------------------------
template <int KTOT, bool FC1>
__global__ __launch_bounds__(512) void k_fcw(const __hip_bfloat16* __restrict__ Asrc,
                                             const __hip_bfloat16* __restrict__ wB,
                                             const float* __restrict__ bias,
                                             const unsigned* __restrict__ wl,
                                             const unsigned* __restrict__ off,
                                             __hip_bfloat16* __restrict__ hbuf,
                                             __hip_bfloat16* __restrict__ tfeats,
                                             float* __restrict__ rootfeat,
                                             int level) {
  __shared__ alignas(16) short As[256 * 64];   // 32 KB
  __shared__ alignas(16) short Bs[128 * 64];   // 16 KB
  __shared__ unsigned wle[256];

  int nwg = (int)gridDim.x;
  int hw = (int)blockIdx.x;
  int q = nwg >> 3, r = nwg & 7;
  int xcd = hw & 7, ii = hw >> 3;
  int wid = (xcd < r ? xcd * (q + 1) : r * (q + 1) + (xcd - r) * q) + ii;
  int nbase = (wid & 7) * 128;     // 8 N-panels of 128
  int mbase = (wid >> 3) * 256;    // M-tiles of 256

  int c0 = (int)off[level];
  int count = (int)off[level + 1] - c0;
  if (mbase >= count) return;
  int t = threadIdx.x, wv = t >> 6, lane = t & 63;
  if (t < 256) wle[t] = wl[c0 + min(mbase + t, count - 1)];
  __syncthreads();

  int lr = lane >> 3, p = lane & 7;
  const __hip_bfloat16* aptrA[4];
  const __hip_bfloat16* aptrB[4];
  const __hip_bfloat16* bptr[2];
  #pragma unroll
  for (int c = 0; c < 4; c++) {
    int rc = (wv * 4 + c) * 8 + lr;    // 0..255: A-row this lane stages
    int u = p ^ (rc & 7);
    if (FC1) {
      unsigned e = wle[rc];
      int bidx = e & 511, s1 = (e >> 9) & 63, s2 = (e >> 15) & 63;
      aptrA[c] = Asrc + (((size_t)(bidx << 6) + s1) << 10) + (u << 3);
      aptrB[c] = Asrc + (((size_t)(bidx << 6) + s2) << 10) + (u << 3);
    } else {
      aptrA[c] = Asrc + ((size_t)(mbase + rc) << 10) + (u << 3);
      aptrB[c] = aptrA[c];
    }
  }
  #pragma unroll
  for (int c = 0; c < 2; c++) {
    int rc = (wv * 2 + c) * 8 + lr;    // 0..127: B-row this lane stages
    int u = p ^ (rc & 7);
    bptr[c] = wB + (size_t)(nbase + rc) * KTOT + (u << 3);
  }

  f32x4 acc[4][4];
  #pragma unroll
  for (int i = 0; i < 4; i++)
    #pragma unroll
    for (int j = 0; j < 4; j++) acc[i][j] = (f32x4){0.f, 0.f, 0.f, 0.f};

  int mh = wv >> 1, nh = wv & 1;       // 4M x 2N wave grid

  for (int k0 = 0; k0 < KTOT; k0 += 64) {
    #pragma unroll
    for (int c = 0; c < 4; c++) {
      int ch = wv * 4 + c;             // 0..31 A-chunks (8 rows each)
      const __hip_bfloat16* g =
          (FC1 && k0 >= DIM) ? (aptrB[c] + (k0 - DIM)) : (aptrA[c] + k0);
      gld16(g, &As[ch << 9]);
    }
    #pragma unroll
    for (int c = 0; c < 2; c++) {
      int ch = wv * 2 + c;             // 0..15 B-chunks
      gld16(bptr[c] + k0, &Bs[ch << 9]);
    }
    __syncthreads();
    #pragma unroll
    for (int kc = 0; kc < 2; kc++) {
      short8 a[4], bb[4];
      #pragma unroll
      for (int mi = 0; mi < 4; mi++) {
        int rr = mh * 64 + mi * 16 + (lane & 15);
        int u = (kc * 4 + (lane >> 4)) ^ (rr & 7);
        a[mi] = *(const short8*)&As[rr * 64 + u * 8];
      }
      #pragma unroll
      for (int ni = 0; ni < 4; ni++) {
        int rr = nh * 64 + ni * 16 + (lane & 15);
        int u = (kc * 4 + (lane >> 4)) ^ (rr & 7);
        bb[ni] = *(const short8*)&Bs[rr * 64 + u * 8];
      }
      #pragma unroll
      for (int mi = 0; mi < 4; mi++)
        #pragma unroll
        for (int ni = 0; ni < 4; ni++)
          acc[mi][ni] = __builtin_amdgcn_mfma_f32_16x16x32_bf16(a[mi], bb[ni],
                                                                acc[mi][ni], 0, 0, 0);
    }
    __syncthreads();
  }

  #pragma unroll
  for (int mi = 0; mi < 4; mi++) {
    #pragma unroll
    for (int reg = 0; reg < 4; reg++) {
      int m_loc = mh * 64 + mi * 16 + ((lane >> 4) << 2) + reg;
      int m = mbase + m_loc;
      if (m >= count) continue;
      #pragma unroll
      for (int ni = 0; ni < 4; ni++) {
        int n = nbase + nh * 64 + ni * 16 + (lane & 15);
        float v = acc[mi][ni][reg] + bias[n];
        if (FC1) {
          hbuf[(size_t)m * DIM + n] = __float2bfloat16(fast_tanh(v));
        } else {
          unsigned e = wle[m_loc];
          int bidx = e & 511, d = (e >> 9) & 63;
          tfeats[(((size_t)(bidx << 6) + d) << 10) + n] = __float2bfloat16(fast_tanh(v));
          if (e >> 21) rootfeat[(size_t)bidx * DIM + n] = v;
        }
      }
    }
  }
}

// ---------------------------------------------------------------------------
// K7n (R21): narrow-tile GEMM for levels >= 2. BM=64 x BN=128, BK=64,
// 8 waves, wave-tile 32x32 (2M x 4N). ~24 KB LDS -> 4 blocks/CU; doubles
// active blocks vs 128^2 (l=2: 512->1024) to hide the sparse A-gather
// latency (measured: 128-tile 390 TF @2/CU vs 700 TF @4/CU). Bit-exact:
// same per-element K order (k0 asc, kc 0/1), same intrinsic/operands.
// ---------------------------------------------------------------------------
template <int KTOT, bool FC1>
__global__ __launch_bounds__(512) void k_fcn(const __hip_bfloat16* __restrict__ Asrc,
                                             const __hip_bfloat16* __restrict__ wB,
                                             const float* __restrict__ bias,
                                             const unsigned* __restrict__ wl,
                                             const unsigned* __restrict__ off,
                                             __hip_bfloat16* __restrict__ hbuf,
                                             __hip_bfloat16* __restrict__ tfeats,
                                             float* __restrict__ rootfeat,
                                             int level) {
  __shared__ alignas(16) short As[64 * 64];    // 8 KB
  __shared__ alignas(16) short Bs[128 * 64];   // 16 KB
  __shared__ unsigned wle[64];

  int nwg = (int)gridDim.x;
  int hw = (int)blockIdx.x;
  int q = nwg >> 3, r = nwg & 7;
  int xcd = hw & 7, ii = hw >> 3;
  int wid = (xcd < r ? xcd * (q + 1) : r * (q + 1) + (xcd - r) * q) + ii;
  int nbase = (wid & 7) * 128;     // 8 N-panels of 128
  int mbase = (wid >> 3) * 64;     // M-tiles of 64

  int c0 = (int)off[level];
  int count = (int)off[level + 1] - c0;
  if (mbase >= count) return;
  int t = threadIdx.x, wv = t >> 6, lane = t & 63;
  if (t < 64) wle[t] = wl[c0 + min(mbase + t, count - 1)];
  __syncthreads();

  int lr = lane >> 3, p = lane & 7;
  const __hip_bfloat16* aptrA;
  const __hip_bfloat16* aptrB;
  const __hip_bfloat16* bptr[2];
  {
    int rc = wv * 8 + lr;              // 0..63: A-row this lane stages
    int u = p ^ (rc & 7);
    if (FC1) {
      unsigned e = wle[rc];
      int bidx = e & 511, s1 = (e >> 9) & 63, s2 = (e >> 15) & 63;
      aptrA = Asrc + (((size_t)(bidx << 6) + s1) << 10) + (u << 3);
      aptrB = Asrc + (((size_t)(bidx << 6) + s2) << 10) + (u << 3);
    } else {
      aptrA = Asrc + ((size_t)(mbase + rc) << 10) + (u << 3);
      aptrB = aptrA;
    }
  }
  #pragma unroll
  for (int c = 0; c < 2; c++) {
    int rc = (wv * 2 + c) * 8 + lr;    // 0..127: B-row this lane stages
    int u = p ^ (rc & 7);
    bptr[c] = wB + (size_t)(nbase + rc) * KTOT + (u << 3);
  }

  f32x4 acc[2][2];
  #pragma unroll
  for (int i = 0; i < 2; i++)
    #pragma unroll
    for (int j = 0; j < 2; j++) acc[i][j] = (f32x4){0.f, 0.f, 0.f, 0.f};

  int mh = wv >> 2, nh = wv & 3;       // 2M x 4N wave grid

  for (int k0 = 0; k0 < KTOT; k0 += 64) {
    {
      const __hip_bfloat16* g =
          (FC1 && k0 >= DIM) ? (aptrB + (k0 - DIM)) : (aptrA + k0);
      gld16(g, &As[wv << 9]);          // 8 A-chunks, one per wave
    }
    #pragma unroll
    for (int c = 0; c < 2; c++) {
      int ch = wv * 2 + c;             // 0..15 B-chunks
      gld16(bptr[c] + k0, &Bs[ch << 9]);
    }
    __syncthreads();
    #pragma unroll
    for (int kc = 0; kc < 2; kc++) {
      short8 a[2], bb[2];
      #pragma unroll
      for (int mi = 0; mi < 2; mi++) {
        int rr = mh * 32 + mi * 16 + (lane & 15);
        int u = (kc * 4 + (lane >> 4)) ^ (rr & 7);
        a[mi] = *(const short8*)&As[rr * 64 + u * 8];
      }
      #pragma unroll
      for (int ni = 0; ni < 2; ni++) {
        int rn = nh * 32 + ni * 16 + (lane & 15);
        int u = (kc * 4 + (lane >> 4)) ^ (rn & 7);
        bb[ni] = *(const short8*)&Bs[rn * 64 + u * 8];
      }
      #pragma unroll
      for (int mi = 0; mi < 2; mi++)
        #pragma unroll
        for (int ni = 0; ni < 2; ni++)
          acc[mi][ni] = __builtin_amdgcn_mfma_f32_16x16x32_bf16(a[mi], bb[ni],
                                                                acc[mi][ni], 0, 0, 0);
    }
    __syncthreads();
  }

  #pragma unroll
  for (int mi = 0; mi < 2; mi++) {
    #pragma unroll
    for (int reg = 0; reg < 4; reg++) {
      int m_loc = mh * 32 + mi * 16 + ((lane >> 4) << 2) + reg;
      int m = mbase + m_loc;
      if (m >= count) continue;
      #pragma unroll
      for (int ni = 0; ni < 2; ni++) {
        int n = nbase + nh * 32 + ni * 16 + (lane & 15);
        float v = acc[mi][ni][reg] + bias[n];
        if (FC1) {
          hbuf[(size_t)m * DIM + n] = __float2bfloat16(fast_tanh(v));
        } else {
          unsigned e = wle[m_loc];
          int bidx = e & 511, d = (e >> 9) & 63;
          tfeats[(((size_t)(bidx << 6) + d) << 10) + n] = __float2bfloat16(fast_tanh(v));
          if (e >> 21) rootfeat[(size_t)bidx * DIM + n] = v;
        }
      }
    }
  }
}

// ---------------------------------------------------------------------------
// K7b: deep-level fallback (> LMAX) + fused final scores. One block per bag.
// ---------------------------------------------------------------------------
#define XP(i) ((i) + ((i) >> 3))
__global__ __launch_bounds__(1024) void k_deep(__hip_bfloat16* __restrict__ tfeats,
                                               const __hip_bfloat16* __restrict__ w1b,
                                               const float* __restrict__ b1,
                                               const __hip_bfloat16* __restrict__ w2b,
                                               const float* __restrict__ b2,
                                               const unsigned* __restrict__ lvlbuf,
                                               float* __restrict__ rootfeat,
                                               const float* __restrict__ rel,
                                               float* __restrict__ out) {
  int b = blockIdx.x;
  __shared__ float xs[XP(2048) + 1];
  __shared__ float hs[XP(1024) + 1];
  __shared__ unsigned steps[NSTEP];
  int t = threadIdx.x, wv = t >> 6, lane = t & 63;
  if (t < NSTEP) steps[t] = lvlbuf[b * NSTEP + t];
  __syncthreads();

  for (int s = 0; s < NSTEP; s++) {
    unsigned e = steps[s];
    int lvl = (int)((e >> 12) & 63);
    if (lvl <= LMAX) continue;
    int i1 = (int)(e & 63), i2 = (int)((e >> 6) & 63);
    const __hip_bfloat16* r1 = tfeats + ((((size_t)b << 6) + i1) << 10);
    const __hip_bfloat16* r2 = tfeats + ((((size_t)b << 6) + i2) << 10);
    xs[XP(t)] = __bfloat162float(r1[t]);
    xs[XP(1024 + t)] = __bfloat162float(r2[t]);
    __syncthreads();
    for (int r = 0; r < 64; r++) {
      int n = r * 16 + wv;
      const short8* wr = (const short8*)(w1b + (size_t)n * 2048);
      float acc = 0.f;
      for (int c = lane; c < 256; c += 64) {
        short8 w8 = wr[c];
        #pragma unroll
        for (int j = 0; j < 8; j++) {
          float wf = __uint_as_float(((unsigned)(unsigned short)w8[j]) << 16);
          acc += xs[XP(c * 8 + j)] * wf;
        }
      }
      for (int off = 32; off; off >>= 1) acc += __shfl_xor(acc, off);
      if (lane == 0) hs[XP(n)] = fast_tanh(acc + b1[n]);
    }
    __syncthreads();
    for (int r = 0; r < 64; r++) {
      int n = r * 16 + wv;
      const short8* wr = (const short8*)(w2b + (size_t)n * 1024);
      float acc = 0.f;
      for (int c = lane; c < 128; c += 64) {
        short8 w8 = wr[c];
        #pragma unroll
        for (int j = 0; j < 8; j++) {
          float wf = __uint_as_float(((unsigned)(unsigned short)w8[j]) << 16);
          acc += hs[XP(c * 8 + j)] * wf;
        }
      }
      for (int off = 32; off; off >>= 1) acc += __shfl_xor(acc, off);
      if (lane == 0) {
        float f = acc + b2[n];
        tfeats[((((size_t)b << 6) + i1) << 10) + n] = __float2bfloat16(fast_tanh(f));
        if (s == NSTEP - 1) rootfeat[(size_t)b * DIM + n] = f;
      }
    }
    __syncthreads();
  }

  // ---- fused scores: sigmoid(rootfeat[b] @ rel^T)
  __shared__ float fr[DIM];
  fr[t] = rootfeat[(size_t)b * DIM + t];
  __syncthreads();
  for (int c = wv; c < NCLS; c += 16) {
    const float* w = rel + (size_t)c * DIM;
    float acc = 0.f;
    for (int jx = lane; jx < DIM; jx += 64) acc += fr[jx] * w[jx];
    for (int off = 32; off; off >>= 1) acc += __shfl_xor(acc, off);
    if (lane == 0) out[b * NCLS + c] = 1.0f / (1.0f + expf(-acc));
  }
}

// ---------------------------------------------------------------------------
extern "C" void kernel_launch(void* const* d_in, const int* in_sizes, int n_in,
                              void* d_out, int out_size, void* d_ws, size_t ws_size,
                              hipStream_t stream) {
  const float* rep = (const float*)d_in[0];
  const float* w1  = (const float*)d_in[1];
  const float* b1  = (const float*)d_in[2];
  const float* w2  = (const float*)d_in[3];
  const float* b2  = (const float*)d_in[4];
  const float* rel = (const float*)d_in[5];
  float* out = (float*)d_out;

  char* ws = (char*)d_ws;
  __hip_bfloat16* tfeats = (__hip_bfloat16*)ws; ws += (size_t)NBAG * NPB * DIM * 2;
  __hip_bfloat16* hbuf   = (__hip_bfloat16*)ws; ws += (size_t)MAXROWS * DIM * 2;
  __hip_bfloat16* w1b    = (__hip_bfloat16*)ws; ws += (size_t)DIM * 2 * DIM * 2;
  __hip_bfloat16* w2b    = (__hip_bfloat16*)ws; ws += (size_t)DIM * DIM * 2;
  float* rootfeat        = (float*)ws;          ws += (size_t)NBAG * DIM * 4;
  float* nw              = (float*)ws;          ws += (size_t)NBAG * NPB * 4;
  float* inv_g           = (float*)ws;          ws += (size_t)NBAG * NPB * 4;
  unsigned* lvlbuf       = (unsigned*)ws;       ws += (size_t)NBAG * NSTEP * 4;
  unsigned* cnt          = (unsigned*)ws;       ws += (size_t)NBAG * 64 * 4;
  unsigned* bagoff       = (unsigned*)ws;       ws += (size_t)64 * 512 * 4;
  unsigned* levtot       = (unsigned*)ws;       ws += 64 * 4;
  unsigned* off          = (unsigned*)ws;       ws += 128 * 4;
  unsigned* wl           = (unsigned*)ws;       ws += (size_t)NBAG * NSTEP * 4;

  k_prep_a<<<NBAG * 4, 256, 0, stream>>>(rep, inv_g, w1, w1b, w2, w2b);
  k_prep_b<<<NBAG, 1024, 0, stream>>>(rep, inv_g, nw, tfeats);
  k_merge_levels<<<NBAG / 4, 256, 0, stream>>>(nw, lvlbuf, cnt);
  k_bagscan<<<63, 512, 0, stream>>>(cnt, bagoff, levtot);
  k_scatter<<<126, 256, 0, stream>>>(lvlbuf, levtot, bagoff, wl, off);

  // level 1: wide 256x128 tiles (grid 512 = 2/CU; measured 890 TF)
  k_fcw<2 * DIM, true><<<dim3(8 * 64), 512, 0, stream>>>(
      tfeats, w1b, b1, wl, off, hbuf, nullptr, nullptr, 1);
  k_fcw<DIM, false><<<dim3(8 * 64), 512, 0, stream>>>(
      hbuf, w2b, b2, wl, off, nullptr, tfeats, rootfeat, 1);

  // levels 2..LMAX: narrow 64x128 tiles (2x blocks vs 128^2 -> 4 blocks/CU)
  for (int l = 2; l <= LMAX; l++) {
    int cap = 64 / (l + 1); if (cap > 32) cap = 32;
    int capM = 8 * cap;                       // 64-row M-tiles capacity
    k_fcn<2 * DIM, true><<<dim3(8 * capM), 512, 0, stream>>>(
        tfeats, w1b, b1, wl, off, hbuf, nullptr, nullptr, l);
    k_fcn<DIM, false><<<dim3(8 * capM), 512, 0, stream>>>(
        hbuf, w2b, b2, wl, off, nullptr, tfeats, rootfeat, l);
  }
  k_deep<<<NBAG, 1024, 0, stream>>>(tfeats, w1b, b1, w2b, b2, lvlbuf, rootfeat,
                                    rel, out);
}